// Round 5
// baseline (323.933 us; speedup 1.0000x reference)
//
#include <hip/hip_runtime.h>
#include <stdint.h>

#define BB  32
#define CIN 128
#define CO  256
#define HH  64
#define WW  64
#define HW  4096
#define OH  62
#define OW  62
#define OHW 3844
#define OPST 3968   // padded plane stride for t1/t2 (= 31*128)

typedef __attribute__((ext_vector_type(8))) short  short8;   // 8 x bf16
typedef __attribute__((ext_vector_type(4))) float  f32x4;
typedef __attribute__((ext_vector_type(2))) ushort ushort2v; // 4B
typedef __attribute__((ext_vector_type(2))) float  f32x2;    // 8B
typedef __attribute__((ext_vector_type(2))) uint32_t uint2v; // 8B

__device__ __forceinline__ ushort f2bf(float f) {
  uint32_t u = __builtin_bit_cast(uint32_t, f);
  u += 0x7FFFu + ((u >> 16) & 1u);
  return (ushort)(u >> 16);
}
__device__ __forceinline__ float bf2f(ushort h) {
  uint32_t u = ((uint32_t)h) << 16;
  return __builtin_bit_cast(float, u);
}
// swizzled byte offset of logical 16B chunk C in 8-chunk (128B) rows:
// XOR chunk bits 0-2 with row bits 0-2 (disjoint -> involution, phase-free)
__device__ __forceinline__ int swz8(int C) { return (C ^ ((C >> 3) & 7)) << 4; }

// ---- k0: transpose + bf16-cast weights: w[ci][co] -> wt[co][ci] ----
__global__ void k_wt(const float* __restrict__ w, ushort* __restrict__ wt,
                     int kdim, int ndim) {
  int e = blockIdx.x * 256 + threadIdx.x;
  if (e >= kdim * ndim) return;
  int co = e / kdim, ci = e - co * kdim;
  wt[e] = f2bf(w[(size_t)ci * ndim + co]);
}

// ---- GEMM: out NCHW bf16 [b][co][pst_out] = sum_ci src * wt[co][ci] + bias
// Tile: 256 co x 128 hw, 8 waves; wave w owns co [32w, 32w+32). BK=64.
// D: col(lane&15)=co, row((lane>>4)*4+k)=hw -> lane holds 4 consecutive hw.
template<bool GATHER>
__global__ __launch_bounds__(512, 4) void k_gemm(
    const void* __restrict__ src, const ushort* __restrict__ wt,
    const float* __restrict__ bias, ushort* __restrict__ out,
    int pst_src, int pst_out, int ktot)
{
  __shared__ ushort Wq[256 * 64];   // 32 KB, swizzled 16B chunks (8/row)
  __shared__ ushort Xq[128 * 64];   // 16 KB, swizzled 16B chunks (8/row)

  const int t = threadIdx.x;
  const int b = blockIdx.y;
  const int hw0 = blockIdx.x * 128;
  const int w = t >> 6, lane = t & 63, l15 = lane & 15, l4 = lane >> 4;

  // loop-invariant swizzled byte offsets
  int afoff[2][2], bxoff[8][2];
  #pragma unroll
  for (int i = 0; i < 2; ++i)
    #pragma unroll
    for (int kk = 0; kk < 2; ++kk)
      afoff[i][kk] = swz8((w * 32 + i * 16 + l15) * 8 + kk * 4 + l4);
  #pragma unroll
  for (int j = 0; j < 8; ++j)
    #pragma unroll
    for (int kk = 0; kk < 2; ++kk)
      bxoff[j][kk] = swz8((j * 16 + l15) * 8 + kk * 4 + l4);
  // staging offsets: W 4 chunks/thread (seg-fast), X 2 chunks/thread (hw-fast)
  int wstoff[4], xstoff[2];
  #pragma unroll
  for (int p = 0; p < 4; ++p) wstoff[p] = swz8(p * 512 + t);
  const int xhw = t & 127;
  #pragma unroll
  for (int p = 0; p < 2; ++p) {
    int c = p * 512 + t, seg = c >> 7;
    xstoff[p] = swz8(xhw * 8 + seg);
  }

  const float bias0 = bias[w * 32 + l15];
  const float bias1 = bias[w * 32 + 16 + l15];

  f32x4 acc[2][8];
  #pragma unroll
  for (int i = 0; i < 2; ++i)
    #pragma unroll
    for (int j = 0; j < 8; ++j)
      #pragma unroll
      for (int k = 0; k < 4; ++k) acc[i][j][k] = 0.f;

  const int ksteps = ktot >> 6;
  for (int ks = 0; ks < ksteps; ++ks) {
    const int ci0 = ks * 64;
    __syncthreads();
    // ---- stage W: 256co x 64ci (4 chunks/thread, seg-fast: coalesced) ----
    #pragma unroll
    for (int p = 0; p < 4; ++p) {
      int c = p * 512 + t, co = c >> 3, seg = c & 7;
      short8 v = *(const short8*)(wt + (size_t)co * ktot + ci0 + seg * 8);
      *(short8*)((char*)Wq + wstoff[p]) = v;
    }
    // ---- stage X: 128hw x 64ci (2 chunks/thread, hw-fast gather) ----
    #pragma unroll
    for (int p = 0; p < 2; ++p) {
      int seg = (p * 512 + t) >> 7;
      short8 xv;
      if (GATHER) {
        const float* xp = (const float*)src
            + ((size_t)b * ktot + ci0 + seg * 8) * pst_src + hw0 + xhw;
        #pragma unroll
        for (int ii = 0; ii < 8; ++ii) xv[ii] = (short)f2bf(xp[(size_t)ii * pst_src]);
      } else {
        const ushort* xp = (const ushort*)src
            + ((size_t)b * ktot + ci0 + seg * 8) * pst_src + hw0 + xhw;
        #pragma unroll
        for (int ii = 0; ii < 8; ++ii) xv[ii] = (short)xp[(size_t)ii * pst_src];
      }
      *(short8*)((char*)Xq + xstoff[p]) = xv;
    }
    __syncthreads();

    // ---- compute: 32 MFMA / wave / kstep ----
    #pragma unroll
    for (int kk = 0; kk < 2; ++kk) {
      short8 af0 = *(const short8*)((char*)Wq + afoff[0][kk]);
      short8 af1 = *(const short8*)((char*)Wq + afoff[1][kk]);
      #pragma unroll
      for (int j = 0; j < 8; ++j) {
        short8 bx = *(const short8*)((char*)Xq + bxoff[j][kk]);
        acc[0][j] = __builtin_amdgcn_mfma_f32_16x16x32_bf16(bx, af0, acc[0][j], 0, 0, 0);
        acc[1][j] = __builtin_amdgcn_mfma_f32_16x16x32_bf16(bx, af1, acc[1][j], 0, 0, 0);
      }
    }
  }

  // ---- epilogue: direct vectorized stores (4 consecutive hw per lane) ----
  #pragma unroll
  for (int i = 0; i < 2; ++i) {
    const float bi = i ? bias1 : bias0;
    const int co = w * 32 + i * 16 + l15;
    ushort* ob = out + (size_t)(b * CO + co) * pst_out + hw0 + l4 * 4;
    #pragma unroll
    for (int j = 0; j < 8; ++j) {
      uint32_t lo = (uint32_t)f2bf(acc[i][j][0] + bi)
                  | ((uint32_t)f2bf(acc[i][j][1] + bi) << 16);
      uint32_t hi = (uint32_t)f2bf(acc[i][j][2] + bi)
                  | ((uint32_t)f2bf(acc[i][j][3] + bi) << 16);
      uint2v v; v[0] = lo; v[1] = hi;
      *(uint2v*)(ob + j * 16) = v;
    }
  }
}

// ---- dw1: V1 (along H) + H1 (along W), VALID. Block = (b,c) plane.
// 8 groups of 32 lanes; group g owns output rows [8g, 8g+7]; lane l owns
// output cols 2l, 2l+1. Branchless fixed-trip: 10 clamped row loads upfront,
// fully unrolled straight-line compute (ILP hides HBM latency).
__global__ __launch_bounds__(256) void k_dw1(
    const ushort* __restrict__ y1, const float* __restrict__ vw,
    const float* __restrict__ vb, const float* __restrict__ hwv,
    const float* __restrict__ hb, ushort* __restrict__ t1)
{
  const int t = threadIdx.x, c = blockIdx.x, b = blockIdx.y;
  const int g = t >> 5, l = t & 31;
  const float v0 = vw[c * 3 + 0], v1 = vw[c * 3 + 1], v2 = vw[c * 3 + 2];
  const float q0 = hwv[c * 3 + 0], q1 = hwv[c * 3 + 1], q2 = hwv[c * 3 + 2];
  const float cst = vb[c] * (q0 + q1 + q2) + hb[c];

  const ushort* src = y1 + ((size_t)b * CO + c) * HW;
  ushort*       dst = t1 + ((size_t)b * CO + c) * OPST;
  const int h0s = g * 8;
  const int w0 = 2 * l;                       // 0..62

  float xa[10], xb[10];
  #pragma unroll
  for (int it = 0; it < 10; ++it) {
    int rc = h0s + it; rc = rc > HH - 1 ? HH - 1 : rc;   // clamp (dup rows ok)
    ushort2v px = *(const ushort2v*)(src + rc * WW + w0);
    xa[it] = bf2f(px[0]); xb[it] = bf2f(px[1]);
  }
  const bool wok = (l < 31);
  #pragma unroll
  for (int it = 2; it < 10; ++it) {
    float vva = v0 * xa[it - 2] + v1 * xa[it - 1] + v2 * xa[it];
    float vvb = v0 * xb[it - 2] + v1 * xb[it - 1] + v2 * xb[it];
    float vvc = __shfl_down(vva, 1, 32);      // vv[w0+2]
    float vvd = __shfl_down(vvb, 1, 32);      // vv[w0+3]
    int h = h0s + it - 2;
    if (h < OH && wok) {
      ushort2v o;
      o[0] = f2bf(cst + q0 * vva + q1 * vvb + q2 * vvc);
      o[1] = f2bf(cst + q0 * vvb + q1 * vvc + q2 * vvd);
      *(ushort2v*)(dst + h * OW + w0) = o;
    }
  }
}

// ---- dw2: zero-pad + V2 + H2; block = (b,c); reads padded-stride t2,
// writes exact fp32 NCHW output. Branchless fixed-trip, masked pad.
__global__ __launch_bounds__(256) void k_dw2(
    const ushort* __restrict__ t2, const float* __restrict__ vw,
    const float* __restrict__ vb, const float* __restrict__ hwv,
    const float* __restrict__ hb, float* __restrict__ outp)
{
  const int t = threadIdx.x, c = blockIdx.x, b = blockIdx.y;
  const int g = t >> 5, l = t & 31;
  const float v0 = vw[c * 3 + 0], v1 = vw[c * 3 + 1], v2 = vw[c * 3 + 2];
  const float q0 = hwv[c * 3 + 0], q1 = hwv[c * 3 + 1], q2 = hwv[c * 3 + 2];
  const float cst = vb[c] * (q0 + q1 + q2) + hb[c];

  const ushort* srcp = t2   + ((size_t)b * CO + c) * OPST;
  float*        dst  = outp + ((size_t)b * CO + c) * OHW;
  const int h0s = g * 8;
  const int w0 = 2 * l;                       // 0..62; l=31 is a pad lane

  float xa[10], xb[10];
  #pragma unroll
  for (int it = 0; it < 10; ++it) {
    int r = h0s - 1 + it;
    int rc = r < 0 ? 0 : (r > OH - 1 ? OH - 1 : r);
    ushort2v px = *(const ushort2v*)(srcp + rc * OW + w0);  // in-plane (stride OPST)
    float m = (r >= 0 && r < OH && l < 31) ? 1.f : 0.f;     // pad -> 0
    xa[it] = m * bf2f(px[0]); xb[it] = m * bf2f(px[1]);
  }
  const bool wok = (l < 31);
  #pragma unroll
  for (int j = 0; j < 8; ++j) {
    float vva = v0 * xa[j] + v1 * xa[j + 1] + v2 * xa[j + 2];
    float vvb = v0 * xb[j] + v1 * xb[j + 1] + v2 * xb[j + 2];
    float vvL = __shfl_up(vvb, 1, 32);        // vv[w0-1]
    float vvR = __shfl_down(vva, 1, 32);      // vv[w0+2]
    if (l == 0) vvL = 0.f;                    // col -1 pad
    int h = h0s + j;
    if (h < OH && wok) {
      f32x2 o;
      o[0] = cst + q0 * vvL + q1 * vva + q2 * vvb;
      o[1] = cst + q0 * vva + q1 * vvb + q2 * vvR;
      *(f32x2*)(dst + h * OW + w0) = o;
    }
  }
}

extern "C" void kernel_launch(void* const* d_in, const int* in_sizes, int n_in,
                              void* d_out, int out_size, void* d_ws, size_t ws_size,
                              hipStream_t stream) {
  const float* x   = (const float*)d_in[0];
  const float* L1w = (const float*)d_in[1];
  const float* L1b = (const float*)d_in[2];
  const float* V1w = (const float*)d_in[3];
  const float* V1b = (const float*)d_in[4];
  const float* H1w = (const float*)d_in[5];
  const float* H1b = (const float*)d_in[6];
  const float* L2w = (const float*)d_in[7];
  const float* L2b = (const float*)d_in[8];
  const float* V2w = (const float*)d_in[9];
  const float* V2b = (const float*)d_in[10];
  const float* H2w = (const float*)d_in[11];
  const float* H2b = (const float*)d_in[12];

  char* ws = (char*)d_ws;
  ushort* y1n = (ushort*)ws;                                 // 67,108,864 B
  ushort* w1t = (ushort*)(ws + (size_t)67108864);            //     65,536 B
  ushort* w2t = (ushort*)(ws + (size_t)67108864 + 65536);    //    131,072 B
  ushort* t2n = (ushort*)ws;                                 // reuse y1n (dead), stride OPST
  ushort* t1n = (ushort*)d_out;                              // d_out scratch, stride OPST

  k_wt<<<dim3((CIN * CO + 255) / 256), dim3(256), 0, stream>>>(L1w, w1t, CIN, CO);
  k_wt<<<dim3((CO * CO + 255) / 256), dim3(256), 0, stream>>>(L2w, w2t, CO, CO);

  // L1: x (fp32 NCHW) -> y1n bf16 NCHW [b][256][4096]
  k_gemm<true><<<dim3(HW / 128, BB), dim3(512), 0, stream>>>(
      (const void*)x, w1t, L1b, y1n, HW, HW, CIN);

  // V1+H1 -> t1n bf16 [b][256][OPST] (in d_out)
  k_dw1<<<dim3(CO, BB), dim3(256), 0, stream>>>(y1n, V1w, V1b, H1w, H1b, t1n);

  // L2: t1n -> t2n bf16 [b][256][OPST]
  k_gemm<false><<<dim3(OPST / 128, BB), dim3(512), 0, stream>>>(
      (const void*)t1n, w2t, L2b, t2n, OPST, OPST, CO);

  // pad + V2 + H2 -> d_out fp32 NCHW
  k_dw2<<<dim3(CO, BB), dim3(256), 0, stream>>>(t2n, V2w, V2b, H2w, H2b, (float*)d_out);
}